// Round 3
// baseline (541.190 us; speedup 1.0000x reference)
//
#include <hip/hip_runtime.h>
#include <hip/hip_bf16.h>

#define S 4096
#define D 256
#define NB 4

typedef __attribute__((ext_vector_type(8))) __bf16 bf16x8;
typedef __attribute__((ext_vector_type(8))) short s16x8;
typedef __attribute__((ext_vector_type(4))) short s16x4;
typedef __attribute__((ext_vector_type(4))) float f32x4;

#define MFMA(a, b, c) __builtin_amdgcn_mfma_f32_16x16x32_bf16(a, b, c, 0, 0, 0)

__device__ __forceinline__ short f2bf(float f) {
    union { float f; unsigned u; } v; v.f = f;
    unsigned r = v.u + 0x7fffu + ((v.u >> 16) & 1u);   // round-to-nearest-even
    return (short)(r >> 16);
}

// ---------------- fused: x->bf16 + sq-norms + V = xW^T+b stored transposed ----------------
// 512 threads / 8 waves, s-tile 64, grid 256. W converted fp32->bf16 into REGISTERS
// before the staging barrier (no prep_w kernel, no global loads in the MFMA loop).
__global__ __launch_bounds__(512) void k_vprojx(const float* __restrict__ x,
                                                const float* __restrict__ Wv,
                                                const float* __restrict__ bv,
                                                short* __restrict__ xb,
                                                float* __restrict__ sqg,
                                                short* __restrict__ vt) {
    __shared__ short sX[64 * 264];
    __shared__ short sT[256 * 72];

    const int b  = blockIdx.x >> 6;
    const int s0 = (blockIdx.x & 63) * 64;
    const int tid = threadIdx.x;
    const int w = tid >> 6, lane = tid & 63;
    const int col = lane & 15, quad = lane >> 4;

    // ---- W preload: wave w owns d-strip [w*32, w*32+32) ----
    bf16x8 wf[2][8];
    #pragma unroll
    for (int ni = 0; ni < 2; ni++)
        #pragma unroll
        for (int ks = 0; ks < 8; ks++) {
            const float* p = Wv + (size_t)(w * 32 + ni * 16 + col) * D + ks * 32 + quad * 8;
            float4 f0 = *(const float4*)p;
            float4 f1 = *(const float4*)(p + 4);
            s16x8 o;
            o[0] = f2bf(f0.x); o[1] = f2bf(f0.y); o[2] = f2bf(f0.z); o[3] = f2bf(f0.w);
            o[4] = f2bf(f1.x); o[5] = f2bf(f1.y); o[6] = f2bf(f1.z); o[7] = f2bf(f1.w);
            wf[ni][ks] = *(bf16x8*)&o;
        }

    // ---- stage x (coalesced: one row per wave per step), convert, row norms ----
    #pragma unroll
    for (int it = 0; it < 8; it++) {
        int row = it * 8 + w;
        float4 v = *(const float4*)(x + (size_t)(b * S + s0 + row) * D + lane * 4);
        float ss = v.x * v.x + v.y * v.y + v.z * v.z + v.w * v.w;
        #pragma unroll
        for (int off = 32; off; off >>= 1) ss += __shfl_xor(ss, off, 64);
        s16x4 o;
        o.x = f2bf(v.x); o.y = f2bf(v.y); o.z = f2bf(v.z); o.w = f2bf(v.w);
        *(s16x4*)(sX + row * 264 + lane * 4) = o;
        *(s16x4*)(xb + (size_t)(b * S + s0 + row) * D + lane * 4) = o;
        if (lane == 0) sqg[b * S + s0 + row] = ss;
    }
    __syncthreads();

    // ---- gemm: acc[4 mi][2 ni], LDS A-reads + register B ----
    f32x4 acc[4][2];
    #pragma unroll
    for (int mi = 0; mi < 4; mi++) {
        acc[mi][0] = (f32x4){0.f, 0.f, 0.f, 0.f};
        acc[mi][1] = (f32x4){0.f, 0.f, 0.f, 0.f};
    }
    #pragma unroll
    for (int ks = 0; ks < 8; ks++) {
        bf16x8 a[4];
        #pragma unroll
        for (int mi = 0; mi < 4; mi++)
            a[mi] = *(const bf16x8*)(sX + (mi * 16 + col) * 264 + ks * 32 + quad * 8);
        #pragma unroll
        for (int mi = 0; mi < 4; mi++) {
            acc[mi][0] = MFMA(a[mi], wf[0][ks], acc[mi][0]);
            acc[mi][1] = MFMA(a[mi], wf[1][ks], acc[mi][1]);
        }
    }

    // ---- bias + transpose-stage + coalesced Vt write ----
    #pragma unroll
    for (int ni = 0; ni < 2; ni++) {
        int d = w * 32 + ni * 16 + col;
        float bvv = bv[d];
        #pragma unroll
        for (int mi = 0; mi < 4; mi++)
            #pragma unroll
            for (int r = 0; r < 4; r++)
                sT[d * 72 + mi * 16 + quad * 4 + r] = f2bf(acc[mi][ni][r] + bvv);
    }
    __syncthreads();
    {
        int d = tid >> 1, half = (tid & 1) * 32;
        short* dst = vt + (size_t)(b * D + d) * S + s0 + half;
        const short* src = sT + d * 72 + half;
        #pragma unroll
        for (int i = 0; i < 4; i++)
            *(s16x8*)(dst + i * 8) = *(const s16x8*)(src + i * 8);
    }
}

// ---------------- Main fused attention ----------------
// 512 threads = 8 waves, 64 q-rows, t-range = S/TSPLIT per block.
// TSPLIT=2: grid 512 -> 2 blocks/CU; raw partials + separate combine.
template <int TSPLIT>
__global__ __launch_bounds__(512, 4) void k_attn(const short* __restrict__ xb,
                                                 const short* __restrict__ vt,
                                                 const float* __restrict__ sq,
                                                 const float* __restrict__ logt,
                                                 float* __restrict__ outp,
                                                 float* __restrict__ p1,
                                                 float* __restrict__ rws) {
    __shared__ short sXt[2][64 * 264];
    __shared__ short sK[64 * 72];
    __shared__ float sRow[64];

    const int tid = threadIdx.x;
    const int w = tid >> 6, lane = tid & 63;
    const int col = lane & 15, quad = lane >> 4;
    const int qh = w >> 2, tq = w & 3;

    int b, th, qt;
    if (TSPLIT == 2) {            // XCD swizzle: blockIdx&7 -> (batch, t-half)
        b = (blockIdx.x & 7) >> 1;
        th = blockIdx.x & 1;
        qt = blockIdx.x >> 3;
    } else {
        b = blockIdx.x & 3;
        th = 0;
        qt = blockIdx.x >> 2;
    }
    const int q0 = qt * 64;
    const int t_base = th * (S / TSPLIT);
    const int NT = (S / TSPLIT) / 64;

    float temp = fmaxf(__expf(logt[0]), 1e-5f);
    float t2 = temp * temp;

    const short* xtb = xb + (size_t)b * S * D;
    const short* vtb = vt + (size_t)b * D * S;
    const float* sqb = sq + b * S;

    if (tid < 64) sRow[tid] = 0.f;

    bf16x8 xq[2][8];
    #pragma unroll
    for (int mi = 0; mi < 2; mi++)
        #pragma unroll
        for (int ks = 0; ks < 8; ks++)
            xq[mi][ks] = *(const bf16x8*)(xtb + (size_t)(q0 + qh * 32 + mi * 16 + col) * D + ks * 32 + quad * 8);

    float sqq[2][4];
    #pragma unroll
    for (int mi = 0; mi < 2; mi++)
        #pragma unroll
        for (int rr = 0; rr < 4; rr++)
            sqq[mi][rr] = sqb[q0 + qh * 32 + mi * 16 + quad * 4 + rr];

    f32x4 acc[4][2];
    #pragma unroll
    for (int mi = 0; mi < 4; mi++) {
        acc[mi][0] = (f32x4){0.f, 0.f, 0.f, 0.f};
        acc[mi][1] = (f32x4){0.f, 0.f, 0.f, 0.f};
    }
    float rs[2][4] = {{0.f, 0.f, 0.f, 0.f}, {0.f, 0.f, 0.f, 0.f}};

    // prologue: stage first tile
    #pragma unroll
    for (int p = 0; p < 4; p++) {
        int c = p * 512 + tid;
        int row = c >> 5, cc = c & 31;
        s16x8 v = *(const s16x8*)(xtb + (size_t)(t_base + row) * D + cc * 8);
        *(s16x8*)(&sXt[0][row * 264 + cc * 8]) = v;
    }

    for (int i = 0; i < NT; i++) {
        const int t0 = t_base + i * 64;
        const int cur = i & 1, nxt = cur ^ 1;
        __syncthreads();   // Ba: sXt[cur] staged, sK free

        bf16x8 vb[2][2];
        #pragma unroll
        for (int ni = 0; ni < 2; ni++)
            #pragma unroll
            for (int kt = 0; kt < 2; kt++)
                vb[ni][kt] = *(const bf16x8*)(vtb + (size_t)(w * 32 + ni * 16 + col) * S + t0 + kt * 32 + quad * 8);

        const int t0n = (i < NT - 1) ? t0 + 64 : t_base;
        s16x8 st[4];
        int srow[4], scc[4];
        #pragma unroll
        for (int p = 0; p < 4; p++) {
            int c = p * 512 + tid;
            srow[p] = c >> 5; scc[p] = c & 31;
            st[p] = *(const s16x8*)(xtb + (size_t)(t0n + srow[p]) * D + scc[p] * 8);
        }

        float sqt = sqb[t0 + tq * 16 + col];

        f32x4 p2[2];
        p2[0] = (f32x4){0.f, 0.f, 0.f, 0.f};
        p2[1] = (f32x4){0.f, 0.f, 0.f, 0.f};
        #pragma unroll
        for (int ks = 0; ks < 8; ks++) {
            bf16x8 bfr = *(const bf16x8*)(&sXt[cur][(tq * 16 + col) * 264 + ks * 32 + quad * 8]);
            p2[0] = MFMA(xq[0][ks], bfr, p2[0]);
            p2[1] = MFMA(xq[1][ks], bfr, p2[1]);
        }

        const int tglob = t0 + tq * 16 + col;
        #pragma unroll
        for (int mi = 0; mi < 2; mi++)
            #pragma unroll
            for (int rr = 0; rr < 4; rr++) {
                int sl = qh * 32 + mi * 16 + quad * 4 + rr;
                float d2 = fmaxf(sqq[mi][rr] + sqt - 2.f * p2[mi][rr], 0.f);
                float kv = t2 * __builtin_amdgcn_rcpf(t2 + d2);
                if (q0 + sl == tglob) kv = 1.f;   // exact diagonal
                rs[mi][rr] += kv;
                sK[sl * 72 + tq * 16 + col] = f2bf(kv);
            }

        __syncthreads();   // Bb: sK visible

        #pragma unroll
        for (int p = 0; p < 4; p++)
            *(s16x8*)(&sXt[nxt][srow[p] * 264 + scc[p] * 8]) = st[p];

        #pragma unroll
        for (int kt = 0; kt < 2; kt++)
            #pragma unroll
            for (int mi = 0; mi < 4; mi++) {
                bf16x8 af = *(const bf16x8*)(&sK[(mi * 16 + col) * 72 + kt * 32 + quad * 8]);
                acc[mi][0] = MFMA(af, vb[0][kt], acc[mi][0]);
                acc[mi][1] = MFMA(af, vb[1][kt], acc[mi][1]);
            }
    }

    // ---- epilogue ----
    #pragma unroll
    for (int mi = 0; mi < 2; mi++)
        #pragma unroll
        for (int rr = 0; rr < 4; rr++) {
            float v = rs[mi][rr];
            v += __shfl_xor(v, 1, 64);
            v += __shfl_xor(v, 2, 64);
            v += __shfl_xor(v, 4, 64);
            v += __shfl_xor(v, 8, 64);
            if (col == 0) atomicAdd(&sRow[qh * 32 + mi * 16 + quad * 4 + rr], v);
        }
    __syncthreads();

    if (TSPLIT == 2) {
        if (tid < 64) rws[(size_t)th * NB * S + b * S + q0 + tid] = sRow[tid];
        float* ob = (th ? p1 : outp) + (size_t)(b * S + q0) * D;
        #pragma unroll
        for (int mi = 0; mi < 4; mi++)
            #pragma unroll
            for (int rr = 0; rr < 4; rr++)
                #pragma unroll
                for (int ni = 0; ni < 2; ni++)
                    ob[(size_t)(mi * 16 + quad * 4 + rr) * D + w * 32 + ni * 16 + col] =
                        acc[mi][ni][rr];
    } else {
        float* ob = outp + (size_t)(b * S + q0) * D;
        #pragma unroll
        for (int mi = 0; mi < 4; mi++)
            #pragma unroll
            for (int rr = 0; rr < 4; rr++) {
                float rinv = __builtin_amdgcn_rcpf(fmaxf(sRow[mi * 16 + quad * 4 + rr], 1e-8f));
                #pragma unroll
                for (int ni = 0; ni < 2; ni++)
                    ob[(size_t)(mi * 16 + quad * 4 + rr) * D + w * 32 + ni * 16 + col] =
                        acc[mi][ni][rr] * rinv;
            }
    }
}

// ---------------- combine: out = (O0 + O1) / (r0 + r1) ----------------
__global__ __launch_bounds__(256) void k_combine(float* __restrict__ outp,
                                                 const float* __restrict__ p1,
                                                 const float* __restrict__ rws) {
    int i4 = blockIdx.x * 256 + threadIdx.x;
    int gs = i4 >> 6;   // D/4 = 64 float4 per row
    float rinv = __builtin_amdgcn_rcpf(fmaxf(rws[gs] + rws[(size_t)NB * S + gs], 1e-8f));
    float4 o0 = ((const float4*)outp)[i4];
    float4 o1 = ((const float4*)p1)[i4];
    float4 o;
    o.x = (o0.x + o1.x) * rinv;
    o.y = (o0.y + o1.y) * rinv;
    o.z = (o0.z + o1.z) * rinv;
    o.w = (o0.w + o1.w) * rinv;
    ((float4*)outp)[i4] = o;
}

extern "C" void kernel_launch(void* const* d_in, const int* in_sizes, int n_in,
                              void* d_out, int out_size, void* d_ws, size_t ws_size,
                              hipStream_t stream) {
    const float* x    = (const float*)d_in[0];
    const float* Wv   = (const float*)d_in[1];
    const float* bv   = (const float*)d_in[2];
    const float* logt = (const float*)d_in[3];
    float* out = (float*)d_out;

    char* ws = (char*)d_ws;
    short* xb  = (short*)ws;                          // bf16 x   [B][S][D]   8 MB
    short* vt  = (short*)(ws + 8388608);              // bf16 V^T [B][D][S]   8 MB
    float* sq  = (float*)(ws + 16777216);             // ||x||^2  [B][S]      64 KB
    float* rws = (float*)(ws + 16842752);             // rowsums  [2][B][S]   128 KB
    float* p1  = (float*)(ws + 16973824);             // partial O (t-half 1) 16.78 MB
    const size_t need_split = 16973824u + (size_t)NB * S * D * 4u;

    k_vprojx<<<NB * (S / 64), 512, 0, stream>>>(x, Wv, bv, xb, sq, vt);

    if (ws_size >= need_split) {
        k_attn<2><<<NB * (S / 64) * 2, 512, 0, stream>>>(xb, vt, sq, logt, out, p1, rws);
        k_combine<<<(NB * S * D / 4) / 256, 256, 0, stream>>>(out, p1, rws);
    } else {
        k_attn<1><<<NB * (S / 64), 512, 0, stream>>>(xb, vt, sq, logt, out, nullptr, nullptr);
    }
}

// Round 4
// 228.748 us; speedup vs baseline: 2.3659x; 2.3659x over previous
//
#include <hip/hip_runtime.h>
#include <hip/hip_bf16.h>

#define S 4096
#define D 256
#define NB 4

typedef __attribute__((ext_vector_type(8))) __bf16 bf16x8;
typedef __attribute__((ext_vector_type(8))) short s16x8;
typedef __attribute__((ext_vector_type(4))) short s16x4;
typedef __attribute__((ext_vector_type(4))) float f32x4;

#define MFMA(a, b, c) __builtin_amdgcn_mfma_f32_16x16x32_bf16(a, b, c, 0, 0, 0)

__device__ __forceinline__ short f2bf(float f) {
    union { float f; unsigned u; } v; v.f = f;
    unsigned r = v.u + 0x7fffu + ((v.u >> 16) & 1u);   // round-to-nearest-even
    return (short)(r >> 16);
}

// ---------------- fused: x->bf16 + sq-norms + V = xW^T+b stored transposed ----------------
__global__ __launch_bounds__(512) void k_vprojx(const float* __restrict__ x,
                                                const float* __restrict__ Wv,
                                                const float* __restrict__ bv,
                                                short* __restrict__ xb,
                                                float* __restrict__ sqg,
                                                short* __restrict__ vt) {
    __shared__ short sX[64 * 264];
    __shared__ short sT[256 * 72];

    const int b  = blockIdx.x >> 6;
    const int s0 = (blockIdx.x & 63) * 64;
    const int tid = threadIdx.x;
    const int w = tid >> 6, lane = tid & 63;
    const int col = lane & 15, quad = lane >> 4;

    // ---- W preload: wave w owns d-strip [w*32, w*32+32) ----
    bf16x8 wf[2][8];
    #pragma unroll
    for (int ni = 0; ni < 2; ni++)
        #pragma unroll
        for (int ks = 0; ks < 8; ks++) {
            const float* p = Wv + (size_t)(w * 32 + ni * 16 + col) * D + ks * 32 + quad * 8;
            float4 f0 = *(const float4*)p;
            float4 f1 = *(const float4*)(p + 4);
            s16x8 o;
            o[0] = f2bf(f0.x); o[1] = f2bf(f0.y); o[2] = f2bf(f0.z); o[3] = f2bf(f0.w);
            o[4] = f2bf(f1.x); o[5] = f2bf(f1.y); o[6] = f2bf(f1.z); o[7] = f2bf(f1.w);
            wf[ni][ks] = *(bf16x8*)&o;
        }

    // ---- stage x (coalesced), convert, row norms ----
    #pragma unroll
    for (int it = 0; it < 8; it++) {
        int row = it * 8 + w;
        float4 v = *(const float4*)(x + (size_t)(b * S + s0 + row) * D + lane * 4);
        float ss = v.x * v.x + v.y * v.y + v.z * v.z + v.w * v.w;
        #pragma unroll
        for (int off = 32; off; off >>= 1) ss += __shfl_xor(ss, off, 64);
        s16x4 o;
        o.x = f2bf(v.x); o.y = f2bf(v.y); o.z = f2bf(v.z); o.w = f2bf(v.w);
        *(s16x4*)(sX + row * 264 + lane * 4) = o;
        *(s16x4*)(xb + (size_t)(b * S + s0 + row) * D + lane * 4) = o;
        if (lane == 0) sqg[b * S + s0 + row] = ss;
    }
    __syncthreads();

    // ---- gemm ----
    f32x4 acc[4][2];
    #pragma unroll
    for (int mi = 0; mi < 4; mi++) {
        acc[mi][0] = (f32x4){0.f, 0.f, 0.f, 0.f};
        acc[mi][1] = (f32x4){0.f, 0.f, 0.f, 0.f};
    }
    #pragma unroll
    for (int ks = 0; ks < 8; ks++) {
        bf16x8 a[4];
        #pragma unroll
        for (int mi = 0; mi < 4; mi++)
            a[mi] = *(const bf16x8*)(sX + (mi * 16 + col) * 264 + ks * 32 + quad * 8);
        #pragma unroll
        for (int mi = 0; mi < 4; mi++) {
            acc[mi][0] = MFMA(a[mi], wf[0][ks], acc[mi][0]);
            acc[mi][1] = MFMA(a[mi], wf[1][ks], acc[mi][1]);
        }
    }

    // ---- bias + transpose-stage + coalesced Vt write ----
    #pragma unroll
    for (int ni = 0; ni < 2; ni++) {
        int d = w * 32 + ni * 16 + col;
        float bvv = bv[d];
        #pragma unroll
        for (int mi = 0; mi < 4; mi++)
            #pragma unroll
            for (int r = 0; r < 4; r++)
                sT[d * 72 + mi * 16 + quad * 4 + r] = f2bf(acc[mi][ni][r] + bvv);
    }
    __syncthreads();
    {
        int d = tid >> 1, half = (tid & 1) * 32;
        short* dst = vt + (size_t)(b * D + d) * S + s0 + half;
        const short* src = sT + d * 72 + half;
        #pragma unroll
        for (int i = 0; i < 4; i++)
            *(s16x8*)(dst + i * 8) = *(const s16x8*)(src + i * 8);
    }
}

// ---------------- Main fused attention ----------------
// 512 threads = 8 waves, 64 q-rows, t-range = S/TSPLIT per block.
// launch_bounds min-waves/EU = 2 (NOT 4: R3 showed 4 forces VGPR<=64 and spills
// xq/acc to scratch -> 1.26GB scratch traffic). At the natural ~112 VGPR the HW
// already co-schedules 2 blocks/CU with grid=512.
template <int TSPLIT>
__global__ __launch_bounds__(512, 2) void k_attn(const short* __restrict__ xb,
                                                 const short* __restrict__ vt,
                                                 const float* __restrict__ sq,
                                                 const float* __restrict__ logt,
                                                 float* __restrict__ outp,
                                                 float* __restrict__ p1,
                                                 float* __restrict__ rws) {
    __shared__ short sXt[2][64 * 264];
    __shared__ short sK[64 * 72];
    __shared__ float sRow[64];

    const int tid = threadIdx.x;
    const int w = tid >> 6, lane = tid & 63;
    const int col = lane & 15, quad = lane >> 4;
    const int qh = w >> 2, tq = w & 3;

    int b, th, qt;
    if (TSPLIT == 2) {            // XCD swizzle: blockIdx&7 -> (batch, t-half)
        b = (blockIdx.x & 7) >> 1;
        th = blockIdx.x & 1;
        qt = blockIdx.x >> 3;
    } else {
        b = blockIdx.x & 3;
        th = 0;
        qt = blockIdx.x >> 2;
    }
    const int q0 = qt * 64;
    const int t_base = th * (S / TSPLIT);
    const int NT = (S / TSPLIT) / 64;

    float temp = fmaxf(__expf(logt[0]), 1e-5f);
    float t2 = temp * temp;

    const short* xtb = xb + (size_t)b * S * D;
    const short* vtb = vt + (size_t)b * D * S;
    const float* sqb = sq + b * S;

    if (tid < 64) sRow[tid] = 0.f;

    bf16x8 xq[2][8];
    #pragma unroll
    for (int mi = 0; mi < 2; mi++)
        #pragma unroll
        for (int ks = 0; ks < 8; ks++)
            xq[mi][ks] = *(const bf16x8*)(xtb + (size_t)(q0 + qh * 32 + mi * 16 + col) * D + ks * 32 + quad * 8);

    float sqq[2][4];
    #pragma unroll
    for (int mi = 0; mi < 2; mi++)
        #pragma unroll
        for (int rr = 0; rr < 4; rr++)
            sqq[mi][rr] = sqb[q0 + qh * 32 + mi * 16 + quad * 4 + rr];

    f32x4 acc[4][2];
    #pragma unroll
    for (int mi = 0; mi < 4; mi++) {
        acc[mi][0] = (f32x4){0.f, 0.f, 0.f, 0.f};
        acc[mi][1] = (f32x4){0.f, 0.f, 0.f, 0.f};
    }
    float rs[2][4] = {{0.f, 0.f, 0.f, 0.f}, {0.f, 0.f, 0.f, 0.f}};

    // prologue: stage first tile
    #pragma unroll
    for (int p = 0; p < 4; p++) {
        int c = p * 512 + tid;
        int row = c >> 5, cc = c & 31;
        s16x8 v = *(const s16x8*)(xtb + (size_t)(t_base + row) * D + cc * 8);
        *(s16x8*)(&sXt[0][row * 264 + cc * 8]) = v;
    }

    for (int i = 0; i < NT; i++) {
        const int t0 = t_base + i * 64;
        const int cur = i & 1, nxt = cur ^ 1;
        __syncthreads();   // Ba: sXt[cur] staged, sK free

        bf16x8 vb[2][2];
        #pragma unroll
        for (int ni = 0; ni < 2; ni++)
            #pragma unroll
            for (int kt = 0; kt < 2; kt++)
                vb[ni][kt] = *(const bf16x8*)(vtb + (size_t)(w * 32 + ni * 16 + col) * S + t0 + kt * 32 + quad * 8);

        const int t0n = (i < NT - 1) ? t0 + 64 : t_base;
        s16x8 st[4];
        int srow[4], scc[4];
        #pragma unroll
        for (int p = 0; p < 4; p++) {
            int c = p * 512 + tid;
            srow[p] = c >> 5; scc[p] = c & 31;
            st[p] = *(const s16x8*)(xtb + (size_t)(t0n + srow[p]) * D + scc[p] * 8);
        }

        float sqt = sqb[t0 + tq * 16 + col];

        f32x4 p2[2];
        p2[0] = (f32x4){0.f, 0.f, 0.f, 0.f};
        p2[1] = (f32x4){0.f, 0.f, 0.f, 0.f};
        #pragma unroll
        for (int ks = 0; ks < 8; ks++) {
            bf16x8 bfr = *(const bf16x8*)(&sXt[cur][(tq * 16 + col) * 264 + ks * 32 + quad * 8]);
            p2[0] = MFMA(xq[0][ks], bfr, p2[0]);
            p2[1] = MFMA(xq[1][ks], bfr, p2[1]);
        }

        const int tglob = t0 + tq * 16 + col;
        #pragma unroll
        for (int mi = 0; mi < 2; mi++)
            #pragma unroll
            for (int rr = 0; rr < 4; rr++) {
                int sl = qh * 32 + mi * 16 + quad * 4 + rr;
                float d2 = fmaxf(sqq[mi][rr] + sqt - 2.f * p2[mi][rr], 0.f);
                float kv = t2 * __builtin_amdgcn_rcpf(t2 + d2);
                if (q0 + sl == tglob) kv = 1.f;   // exact diagonal
                rs[mi][rr] += kv;
                sK[sl * 72 + tq * 16 + col] = f2bf(kv);
            }

        __syncthreads();   // Bb: sK visible

        #pragma unroll
        for (int p = 0; p < 4; p++)
            *(s16x8*)(&sXt[nxt][srow[p] * 264 + scc[p] * 8]) = st[p];

        #pragma unroll
        for (int kt = 0; kt < 2; kt++)
            #pragma unroll
            for (int mi = 0; mi < 4; mi++) {
                bf16x8 af = *(const bf16x8*)(&sK[(mi * 16 + col) * 72 + kt * 32 + quad * 8]);
                acc[mi][0] = MFMA(af, vb[0][kt], acc[mi][0]);
                acc[mi][1] = MFMA(af, vb[1][kt], acc[mi][1]);
            }
    }

    // ---- epilogue ----
    #pragma unroll
    for (int mi = 0; mi < 2; mi++)
        #pragma unroll
        for (int rr = 0; rr < 4; rr++) {
            float v = rs[mi][rr];
            v += __shfl_xor(v, 1, 64);
            v += __shfl_xor(v, 2, 64);
            v += __shfl_xor(v, 4, 64);
            v += __shfl_xor(v, 8, 64);
            if (col == 0) atomicAdd(&sRow[qh * 32 + mi * 16 + quad * 4 + rr], v);
        }
    __syncthreads();

    if (TSPLIT == 2) {
        if (tid < 64) rws[(size_t)th * NB * S + b * S + q0 + tid] = sRow[tid];
        float* ob = (th ? p1 : outp) + (size_t)(b * S + q0) * D;
        #pragma unroll
        for (int mi = 0; mi < 4; mi++)
            #pragma unroll
            for (int rr = 0; rr < 4; rr++)
                #pragma unroll
                for (int ni = 0; ni < 2; ni++)
                    ob[(size_t)(mi * 16 + quad * 4 + rr) * D + w * 32 + ni * 16 + col] =
                        acc[mi][ni][rr];
    } else {
        float* ob = outp + (size_t)(b * S + q0) * D;
        #pragma unroll
        for (int mi = 0; mi < 4; mi++)
            #pragma unroll
            for (int rr = 0; rr < 4; rr++) {
                float rinv = __builtin_amdgcn_rcpf(fmaxf(sRow[mi * 16 + quad * 4 + rr], 1e-8f));
                #pragma unroll
                for (int ni = 0; ni < 2; ni++)
                    ob[(size_t)(mi * 16 + quad * 4 + rr) * D + w * 32 + ni * 16 + col] =
                        acc[mi][ni][rr] * rinv;
            }
    }
}

// ---------------- combine: out = (O0 + O1) / (r0 + r1) ----------------
__global__ __launch_bounds__(256) void k_combine(float* __restrict__ outp,
                                                 const float* __restrict__ p1,
                                                 const float* __restrict__ rws) {
    int i4 = blockIdx.x * 256 + threadIdx.x;
    int gs = i4 >> 6;   // D/4 = 64 float4 per row
    float rinv = __builtin_amdgcn_rcpf(fmaxf(rws[gs] + rws[(size_t)NB * S + gs], 1e-8f));
    float4 o0 = ((const float4*)outp)[i4];
    float4 o1 = ((const float4*)p1)[i4];
    float4 o;
    o.x = (o0.x + o1.x) * rinv;
    o.y = (o0.y + o1.y) * rinv;
    o.z = (o0.z + o1.z) * rinv;
    o.w = (o0.w + o1.w) * rinv;
    ((float4*)outp)[i4] = o;
}

extern "C" void kernel_launch(void* const* d_in, const int* in_sizes, int n_in,
                              void* d_out, int out_size, void* d_ws, size_t ws_size,
                              hipStream_t stream) {
    const float* x    = (const float*)d_in[0];
    const float* Wv   = (const float*)d_in[1];
    const float* bv   = (const float*)d_in[2];
    const float* logt = (const float*)d_in[3];
    float* out = (float*)d_out;

    char* ws = (char*)d_ws;
    short* xb  = (short*)ws;                          // bf16 x   [B][S][D]   8 MB
    short* vt  = (short*)(ws + 8388608);              // bf16 V^T [B][D][S]   8 MB
    float* sq  = (float*)(ws + 16777216);             // ||x||^2  [B][S]      64 KB
    float* rws = (float*)(ws + 16842752);             // rowsums  [2][B][S]   128 KB
    float* p1  = (float*)(ws + 16973824);             // partial O (t-half 1) 16.78 MB
    const size_t need_split = 16973824u + (size_t)NB * S * D * 4u;

    k_vprojx<<<NB * (S / 64), 512, 0, stream>>>(x, Wv, bv, xb, sq, vt);

    if (ws_size >= need_split) {
        k_attn<2><<<NB * (S / 64) * 2, 512, 0, stream>>>(xb, vt, sq, logt, out, p1, rws);
        k_combine<<<(NB * S * D / 4) / 256, 256, 0, stream>>>(out, p1, rws);
    } else {
        k_attn<1><<<NB * (S / 64), 512, 0, stream>>>(xb, vt, sq, logt, out, nullptr, nullptr);
    }
}

// Round 5
// 206.289 us; speedup vs baseline: 2.6235x; 1.1089x over previous
//
#include <hip/hip_runtime.h>
#include <hip/hip_bf16.h>

#define S 4096
#define D 256
#define NB 4

typedef __attribute__((ext_vector_type(8))) __bf16 bf16x8;
typedef __attribute__((ext_vector_type(8))) short s16x8;
typedef __attribute__((ext_vector_type(4))) short s16x4;
typedef __attribute__((ext_vector_type(4))) float f32x4;

#define MFMA(a, b, c) __builtin_amdgcn_mfma_f32_16x16x32_bf16(a, b, c, 0, 0, 0)

__device__ __forceinline__ short f2bf(float f) {
    union { float f; unsigned u; } v; v.f = f;
    unsigned r = v.u + 0x7fffu + ((v.u >> 16) & 1u);   // round-to-nearest-even
    return (short)(r >> 16);
}

// async 16B global -> LDS (wave-uniform base + lane*16 pattern required)
__device__ __forceinline__ void g2lds16(const short* g, short* l) {
    __builtin_amdgcn_global_load_lds(
        (const __attribute__((address_space(1))) unsigned int*)g,
        (__attribute__((address_space(3))) unsigned int*)l, 16, 0, 0);
}

// ---------------- fused: x->bf16(+swizzle) + sq-norms + V = xW^T+b transposed ----------------
// xb layout: within each 512B row, 16B chunk c stored at c ^ (row&7)  (for conflict-free
// unpadded LDS image in k_attn).
__global__ __launch_bounds__(512) void k_vprojx(const float* __restrict__ x,
                                                const float* __restrict__ Wv,
                                                const float* __restrict__ bv,
                                                short* __restrict__ xb,
                                                float* __restrict__ sqg,
                                                short* __restrict__ vt) {
    __shared__ short sX[64 * 264];
    __shared__ short sT[256 * 72];

    const int b  = blockIdx.x >> 6;
    const int s0 = (blockIdx.x & 63) * 64;
    const int tid = threadIdx.x;
    const int w = tid >> 6, lane = tid & 63;
    const int col = lane & 15, quad = lane >> 4;

    // ---- x stage first (longest dependence chain downstream) ----
    #pragma unroll
    for (int it = 0; it < 8; it++) {
        int row = it * 8 + w;
        float4 v = *(const float4*)(x + (size_t)(b * S + s0 + row) * D + lane * 4);
        float ss = v.x * v.x + v.y * v.y + v.z * v.z + v.w * v.w;
        #pragma unroll
        for (int off = 32; off; off >>= 1) ss += __shfl_xor(ss, off, 64);
        s16x4 o;
        o.x = f2bf(v.x); o.y = f2bf(v.y); o.z = f2bf(v.z); o.w = f2bf(v.w);
        *(s16x4*)(sX + row * 264 + lane * 4) = o;
        int sw = (((lane >> 1) ^ (row & 7)) << 3) + (lane & 1) * 4;   // swizzled chunk
        *(s16x4*)(xb + (size_t)(b * S + s0 + row) * D + sw) = o;
        if (lane == 0) sqg[b * S + s0 + row] = ss;
    }

    // ---- W preload: wave w owns d-strip [w*32, w*32+32) ----
    bf16x8 wf[2][8];
    #pragma unroll
    for (int ni = 0; ni < 2; ni++)
        #pragma unroll
        for (int ks = 0; ks < 8; ks++) {
            const float* p = Wv + (size_t)(w * 32 + ni * 16 + col) * D + ks * 32 + quad * 8;
            float4 f0 = *(const float4*)p;
            float4 f1 = *(const float4*)(p + 4);
            s16x8 o;
            o[0] = f2bf(f0.x); o[1] = f2bf(f0.y); o[2] = f2bf(f0.z); o[3] = f2bf(f0.w);
            o[4] = f2bf(f1.x); o[5] = f2bf(f1.y); o[6] = f2bf(f1.z); o[7] = f2bf(f1.w);
            wf[ni][ks] = *(bf16x8*)&o;
        }
    __syncthreads();

    // ---- gemm ----
    f32x4 acc[4][2];
    #pragma unroll
    for (int mi = 0; mi < 4; mi++) {
        acc[mi][0] = (f32x4){0.f, 0.f, 0.f, 0.f};
        acc[mi][1] = (f32x4){0.f, 0.f, 0.f, 0.f};
    }
    #pragma unroll
    for (int ks = 0; ks < 8; ks++) {
        bf16x8 a[4];
        #pragma unroll
        for (int mi = 0; mi < 4; mi++)
            a[mi] = *(const bf16x8*)(sX + (mi * 16 + col) * 264 + ks * 32 + quad * 8);
        #pragma unroll
        for (int mi = 0; mi < 4; mi++) {
            acc[mi][0] = MFMA(a[mi], wf[0][ks], acc[mi][0]);
            acc[mi][1] = MFMA(a[mi], wf[1][ks], acc[mi][1]);
        }
    }

    // ---- bias + transpose-stage + coalesced Vt write ----
    #pragma unroll
    for (int ni = 0; ni < 2; ni++) {
        int d = w * 32 + ni * 16 + col;
        float bvv = bv[d];
        #pragma unroll
        for (int mi = 0; mi < 4; mi++)
            #pragma unroll
            for (int r = 0; r < 4; r++)
                sT[d * 72 + mi * 16 + quad * 4 + r] = f2bf(acc[mi][ni][r] + bvv);
    }
    __syncthreads();
    {
        int d = tid >> 1, half = (tid & 1) * 32;
        short* dst = vt + (size_t)(b * D + d) * S + s0 + half;
        const short* src = sT + d * 72 + half;
        #pragma unroll
        for (int i = 0; i < 4; i++)
            *(s16x8*)(dst + i * 8) = *(const s16x8*)(src + i * 8);
    }
}

// ---------------- Main fused attention ----------------
// 256 threads = 4 waves. q-tile 64, t-tile 32. One __syncthreads per iter:
// async global_load_lds stages Xt[i+1]; gram_i writes sK[i&1]; PV_{i-1} reads sK[(i-1)&1].
// 43.3 KB LDS, ~155 regs -> 3 blocks/CU co-resident.
template <int TSPLIT>
__global__ __launch_bounds__(256) void k_attn(const short* __restrict__ xb,
                                              const short* __restrict__ vt,
                                              const float* __restrict__ sq,
                                              const float* __restrict__ logt,
                                              float* __restrict__ outp,
                                              float* __restrict__ pex,
                                              float* __restrict__ rws) {
    __shared__ short sXt[2][32 * 256];   // unpadded (global_load_lds image), xb pre-swizzled
    __shared__ short sK[2][64 * 40];     // kernel tile [q][t], padded stride 40
    __shared__ float sRow[64];

    const int tid = threadIdx.x;
    const int w = tid >> 6, lane = tid & 63;
    const int col = lane & 15, quad = lane >> 4;
    const int cx = col & 7;

    int b, th, qt;
    if (TSPLIT == 4) {          // xcd = blk&7 -> fixed (b, th&1); th bit1 from blk bit3
        b  = (blockIdx.x >> 1) & 3;
        th = (blockIdx.x & 1) | (((blockIdx.x >> 3) & 1) << 1);
        qt = blockIdx.x >> 4;
    } else if (TSPLIT == 2) {
        b  = (blockIdx.x & 7) >> 1;
        th = blockIdx.x & 1;
        qt = blockIdx.x >> 3;
    } else {
        b = blockIdx.x & 3;
        th = 0;
        qt = blockIdx.x >> 2;
    }
    const int q0 = qt * 64;
    const int t_base = th * (S / TSPLIT);
    const int NT = (S / TSPLIT) / 32;

    float temp = fmaxf(__expf(logt[0]), 1e-5f);
    float t2 = temp * temp;

    const short* xtb = xb + (size_t)b * S * D;
    const short* vtb = vt + (size_t)b * D * S;
    const float* sqb = sq + b * S;

    // gram A-frags: q-rows q0 + w*16 + col (swizzle-aware reads)
    bf16x8 xq[8];
    {
        const short* xrow = xtb + (size_t)(q0 + w * 16 + col) * D;
        #pragma unroll
        for (int ks = 0; ks < 8; ks++)
            xq[ks] = *(const bf16x8*)(xrow + (((ks * 4 + quad) ^ cx) << 3));
    }
    float sqq[4];
    #pragma unroll
    for (int rr = 0; rr < 4; rr++)
        sqq[rr] = sqb[q0 + w * 16 + quad * 4 + rr];

    f32x4 acc[4][4];
    #pragma unroll
    for (int mi = 0; mi < 4; mi++)
        #pragma unroll
        for (int ni = 0; ni < 4; ni++)
            acc[mi][ni] = (f32x4){0.f, 0.f, 0.f, 0.f};
    float rs[4] = {0.f, 0.f, 0.f, 0.f};

    // prologue: async-stage tile 0
    {
        const short* g = xtb + (size_t)t_base * D;
        #pragma unroll
        for (int p = 0; p < 4; p++) {
            int c = p * 256 + tid;
            g2lds16(g + c * 8, &sXt[0][c * 8]);
        }
    }

    for (int i = 0; i < NT; i++) {
        const int t0 = t_base + i * 32;
        const int cur = i & 1;
        __syncthreads();   // staging(i) + sK[(i-1)&1] writes complete; PV_{i-2} reads done

        if (i + 1 < NT) {   // async-stage tile i+1 (uniform branch)
            const short* g = xtb + (size_t)(t0 + 32) * D;
            #pragma unroll
            for (int p = 0; p < 4; p++) {
                int c = p * 256 + tid;
                g2lds16(g + c * 8, &sXt[cur ^ 1][c * 8]);
            }
        }

        // Vt for PV_{i-1} (issue early, consume at end)
        bf16x8 vb[4];
        if (i > 0) {
            const int tp = t0 - 32;
            #pragma unroll
            for (int ni = 0; ni < 4; ni++)
                vb[ni] = *(const bf16x8*)(vtb + (size_t)(w * 64 + ni * 16 + col) * S + tp + quad * 8);
        }
        float sqt0 = sqb[t0 + col], sqt1 = sqb[t0 + 16 + col];

        // ---- gram: P[16 q][32 t] ----
        f32x4 p2v[2];
        p2v[0] = (f32x4){0.f, 0.f, 0.f, 0.f};
        p2v[1] = (f32x4){0.f, 0.f, 0.f, 0.f};
        #pragma unroll
        for (int ks = 0; ks < 8; ks++) {
            int co = ((ks * 4 + quad) ^ cx) << 3;
            bf16x8 b0 = *(const bf16x8*)(&sXt[cur][col * 256 + co]);
            bf16x8 b1 = *(const bf16x8*)(&sXt[cur][(col + 16) * 256 + co]);
            p2v[0] = MFMA(xq[ks], b0, p2v[0]);
            p2v[1] = MFMA(xq[ks], b1, p2v[1]);
        }

        // ---- Cauchy transform + rowsum + sK[cur] write ----
        #pragma unroll
        for (int t_ = 0; t_ < 2; t_++) {
            float sqt = t_ ? sqt1 : sqt0;
            int tg = t0 + t_ * 16 + col;
            #pragma unroll
            for (int rr = 0; rr < 4; rr++) {
                float d2 = fmaxf(sqq[rr] + sqt - 2.f * p2v[t_][rr], 0.f);
                float kv = t2 * __builtin_amdgcn_rcpf(t2 + d2);
                if (q0 + w * 16 + quad * 4 + rr == tg) kv = 1.f;   // exact diagonal
                rs[rr] += kv;
                sK[cur][(w * 16 + quad * 4 + rr) * 40 + t_ * 16 + col] = f2bf(kv);
            }
        }

        // ---- PV_{i-1}: acc[64 q][64 d-strip] += K_{i-1} @ V^T ----
        if (i > 0) {
            #pragma unroll
            for (int mi = 0; mi < 4; mi++) {
                bf16x8 af = *(const bf16x8*)(&sK[cur ^ 1][(mi * 16 + col) * 40 + quad * 8]);
                #pragma unroll
                for (int ni = 0; ni < 4; ni++)
                    acc[mi][ni] = MFMA(af, vb[ni], acc[mi][ni]);
            }
        }
    }

    // ---- epilogue: final PV ----
    __syncthreads();
    {
        const int tp = t_base + (NT - 1) * 32;
        const int cur = (NT - 1) & 1;
        bf16x8 vb[4];
        #pragma unroll
        for (int ni = 0; ni < 4; ni++)
            vb[ni] = *(const bf16x8*)(vtb + (size_t)(w * 64 + ni * 16 + col) * S + tp + quad * 8);
        #pragma unroll
        for (int mi = 0; mi < 4; mi++) {
            bf16x8 af = *(const bf16x8*)(&sK[cur][(mi * 16 + col) * 40 + quad * 8]);
            #pragma unroll
            for (int ni = 0; ni < 4; ni++)
                acc[mi][ni] = MFMA(af, vb[ni], acc[mi][ni]);
        }
    }

    // rowsum: reduce over 16 t-cols in wave; unique writer per q-row
    #pragma unroll
    for (int rr = 0; rr < 4; rr++) {
        float v = rs[rr];
        v += __shfl_xor(v, 1, 64);
        v += __shfl_xor(v, 2, 64);
        v += __shfl_xor(v, 4, 64);
        v += __shfl_xor(v, 8, 64);
        if (col == 0) sRow[w * 16 + quad * 4 + rr] = v;
    }
    __syncthreads();

    if (TSPLIT == 1) {
        float* ob = outp + (size_t)(b * S + q0) * D;
        #pragma unroll
        for (int mi = 0; mi < 4; mi++)
            #pragma unroll
            for (int rr = 0; rr < 4; rr++) {
                float rinv = __builtin_amdgcn_rcpf(fmaxf(sRow[mi * 16 + quad * 4 + rr], 1e-8f));
                #pragma unroll
                for (int ni = 0; ni < 4; ni++)
                    ob[(size_t)(mi * 16 + quad * 4 + rr) * D + w * 64 + ni * 16 + col] =
                        acc[mi][ni][rr] * rinv;
            }
    } else {
        if (tid < 64) rws[(size_t)th * NB * S + b * S + q0 + tid] = sRow[tid];
        float* ob = (th == 0 ? outp : pex + (size_t)(th - 1) * NB * S * D) + (size_t)(b * S + q0) * D;
        #pragma unroll
        for (int mi = 0; mi < 4; mi++)
            #pragma unroll
            for (int rr = 0; rr < 4; rr++)
                #pragma unroll
                for (int ni = 0; ni < 4; ni++)
                    ob[(size_t)(mi * 16 + quad * 4 + rr) * D + w * 64 + ni * 16 + col] =
                        acc[mi][ni][rr];
    }
}

// ---------------- combine: out = sum(partials) / max(sum(rowsums), eps) ----------------
template <int TSPLIT>
__global__ __launch_bounds__(256) void k_combine(float* __restrict__ outp,
                                                 const float* __restrict__ pex,
                                                 const float* __restrict__ rws) {
    int i4 = blockIdx.x * 256 + threadIdx.x;
    int gs = i4 >> 6;   // D/4 = 64 float4 per row
    float sum = rws[gs];
    #pragma unroll
    for (int p = 1; p < TSPLIT; p++) sum += rws[(size_t)p * NB * S + gs];
    float rinv = __builtin_amdgcn_rcpf(fmaxf(sum, 1e-8f));
    float4 o = ((const float4*)outp)[i4];
    #pragma unroll
    for (int p = 1; p < TSPLIT; p++) {
        float4 e = ((const float4*)(pex + (size_t)(p - 1) * NB * S * D))[i4];
        o.x += e.x; o.y += e.y; o.z += e.z; o.w += e.w;
    }
    o.x *= rinv; o.y *= rinv; o.z *= rinv; o.w *= rinv;
    ((float4*)outp)[i4] = o;
}

extern "C" void kernel_launch(void* const* d_in, const int* in_sizes, int n_in,
                              void* d_out, int out_size, void* d_ws, size_t ws_size,
                              hipStream_t stream) {
    const float* x    = (const float*)d_in[0];
    const float* Wv   = (const float*)d_in[1];
    const float* bv   = (const float*)d_in[2];
    const float* logt = (const float*)d_in[3];
    float* out = (float*)d_out;

    char* ws = (char*)d_ws;
    short* xb  = (short*)ws;                          // bf16 x (swizzled) [B][S][D]  8 MB
    short* vt  = (short*)(ws + 8388608);              // bf16 V^T [B][D][S]           8 MB
    float* sq  = (float*)(ws + 16777216);             // ||x||^2  [B][S]              64 KB
    float* rws = (float*)(ws + 16842752);             // rowsums  [T][B][S]
    const size_t P = (size_t)NB * S * D * 4u;         // 16.78 MB per partial

    k_vprojx<<<NB * (S / 64), 512, 0, stream>>>(x, Wv, bv, xb, sq, vt);

    const size_t need4 = 16842752u + 4u * 65536u + 3u * P;
    const size_t need2 = 16842752u + 2u * 65536u + 1u * P;
    if (ws_size >= need4) {
        float* pex = (float*)(ws + 16842752 + 4 * 65536);
        k_attn<4><<<NB * (S / 64) * 4, 256, 0, stream>>>(xb, vt, sq, logt, out, pex, rws);
        k_combine<4><<<(NB * S * D / 4) / 256, 256, 0, stream>>>(out, pex, rws);
    } else if (ws_size >= need2) {
        float* pex = (float*)(ws + 16842752 + 2 * 65536);
        k_attn<2><<<NB * (S / 64) * 2, 256, 0, stream>>>(xb, vt, sq, logt, out, pex, rws);
        k_combine<2><<<(NB * S * D / 4) / 256, 256, 0, stream>>>(out, pex, rws);
    } else {
        k_attn<1><<<NB * (S / 64), 256, 0, stream>>>(xb, vt, sq, logt, out, nullptr, nullptr);
    }
}

// Round 6
// 191.357 us; speedup vs baseline: 2.8282x; 1.0780x over previous
//
#include <hip/hip_runtime.h>
#include <hip/hip_bf16.h>

#define S 4096
#define D 256
#define NB 4

typedef __attribute__((ext_vector_type(8))) __bf16 bf16x8;
typedef __attribute__((ext_vector_type(8))) short s16x8;
typedef __attribute__((ext_vector_type(4))) short s16x4;
typedef __attribute__((ext_vector_type(4))) float f32x4;

#define MFMA(a, b, c) __builtin_amdgcn_mfma_f32_16x16x32_bf16(a, b, c, 0, 0, 0)
#define MFMA8(a, b, c) __builtin_amdgcn_mfma_f32_16x16x32_fp8_fp8(a, b, c, 0, 0, 0)

__device__ __forceinline__ short f2bf(float f) {
    union { float f; unsigned u; } v; v.f = f;
    unsigned r = v.u + 0x7fffu + ((v.u >> 16) & 1u);   // round-to-nearest-even
    return (short)(r >> 16);
}

// async 16B global -> LDS (wave-uniform base + lane*16 pattern required)
__device__ __forceinline__ void g2lds16(const char* g, char* l) {
    __builtin_amdgcn_global_load_lds(
        (const __attribute__((address_space(1))) unsigned int*)g,
        (__attribute__((address_space(3))) unsigned int*)l, 16, 0, 0);
}

// ---------------- fused: x->fp8(+swizzle) + sq-norms + V = xW^T+b transposed ----------------
// xb8 layout: within each 256B fp8 row, 16B chunk c stored at c ^ (row&7)
// (conflict-managed unpadded LDS image for k_attn's global_load_lds staging).
__global__ __launch_bounds__(512) void k_vprojx(const float* __restrict__ x,
                                                const float* __restrict__ Wv,
                                                const float* __restrict__ bv,
                                                unsigned char* __restrict__ xb8,
                                                float* __restrict__ sqg,
                                                short* __restrict__ vt) {
    __shared__ short sX[64 * 264];
    __shared__ short sT[256 * 72];

    const int b  = blockIdx.x >> 6;
    const int s0 = (blockIdx.x & 63) * 64;
    const int tid = threadIdx.x;
    const int w = tid >> 6, lane = tid & 63;
    const int col = lane & 15, quad = lane >> 4;

    // ---- stage x tile, convert bf16->LDS and fp8(swizzled)->global, row norms ----
    #pragma unroll
    for (int it = 0; it < 8; it++) {
        int row = it * 8 + w;
        float4 v = *(const float4*)(x + (size_t)(b * S + s0 + row) * D + lane * 4);
        float ss = v.x * v.x + v.y * v.y + v.z * v.z + v.w * v.w;
        #pragma unroll
        for (int off = 32; off; off >>= 1) ss += __shfl_xor(ss, off, 64);
        s16x4 o;
        o.x = f2bf(v.x); o.y = f2bf(v.y); o.z = f2bf(v.z); o.w = f2bf(v.w);
        *(s16x4*)(sX + row * 264 + lane * 4) = o;
        // fp8 e4m3 packed write (swizzled 16B chunk: (lane>>2) ^ (row&7))
        int p8 = __builtin_amdgcn_cvt_pk_fp8_f32(v.x, v.y, 0, false);
        p8 = __builtin_amdgcn_cvt_pk_fp8_f32(v.z, v.w, p8, true);
        *(int*)(xb8 + (size_t)(b * S + s0 + row) * D +
                (((lane >> 2) ^ (row & 7)) << 4) + (lane & 3) * 4) = p8;
        if (lane == 0) sqg[b * S + s0 + row] = ss;
    }

    // ---- W preload: wave w owns d-strip [w*32, w*32+32) ----
    bf16x8 wf[2][8];
    #pragma unroll
    for (int ni = 0; ni < 2; ni++)
        #pragma unroll
        for (int ks = 0; ks < 8; ks++) {
            const float* p = Wv + (size_t)(w * 32 + ni * 16 + col) * D + ks * 32 + quad * 8;
            float4 f0 = *(const float4*)p;
            float4 f1 = *(const float4*)(p + 4);
            s16x8 o;
            o[0] = f2bf(f0.x); o[1] = f2bf(f0.y); o[2] = f2bf(f0.z); o[3] = f2bf(f0.w);
            o[4] = f2bf(f1.x); o[5] = f2bf(f1.y); o[6] = f2bf(f1.z); o[7] = f2bf(f1.w);
            wf[ni][ks] = *(bf16x8*)&o;
        }
    __syncthreads();

    // ---- gemm ----
    f32x4 acc[4][2];
    #pragma unroll
    for (int mi = 0; mi < 4; mi++) {
        acc[mi][0] = (f32x4){0.f, 0.f, 0.f, 0.f};
        acc[mi][1] = (f32x4){0.f, 0.f, 0.f, 0.f};
    }
    #pragma unroll
    for (int ks = 0; ks < 8; ks++) {
        bf16x8 a[4];
        #pragma unroll
        for (int mi = 0; mi < 4; mi++)
            a[mi] = *(const bf16x8*)(sX + (mi * 16 + col) * 264 + ks * 32 + quad * 8);
        #pragma unroll
        for (int mi = 0; mi < 4; mi++) {
            acc[mi][0] = MFMA(a[mi], wf[0][ks], acc[mi][0]);
            acc[mi][1] = MFMA(a[mi], wf[1][ks], acc[mi][1]);
        }
    }

    // ---- bias + transpose-stage + coalesced Vt write ----
    #pragma unroll
    for (int ni = 0; ni < 2; ni++) {
        int d = w * 32 + ni * 16 + col;
        float bvv = bv[d];
        #pragma unroll
        for (int mi = 0; mi < 4; mi++)
            #pragma unroll
            for (int r = 0; r < 4; r++)
                sT[d * 72 + mi * 16 + quad * 4 + r] = f2bf(acc[mi][ni][r] + bvv);
    }
    __syncthreads();
    {
        int d = tid >> 1, half = (tid & 1) * 32;
        short* dst = vt + (size_t)(b * D + d) * S + s0 + half;
        const short* src = sT + d * 72 + half;
        #pragma unroll
        for (int i = 0; i < 4; i++)
            *(s16x8*)(dst + i * 8) = *(const s16x8*)(src + i * 8);
    }
}

// ---------------- Main fused attention ----------------
// 256 threads = 4 waves. q-tile 64, t-tile 32. Gram in fp8 (A=regs, B=LDS b64 reads),
// PV in bf16 (A=sK LDS, B=Vt global->reg). One __syncthreads per iter.
template <int TSPLIT>
__global__ __launch_bounds__(256) void k_attn(const unsigned char* __restrict__ xb8,
                                              const short* __restrict__ vt,
                                              const float* __restrict__ sq,
                                              const float* __restrict__ logt,
                                              float* __restrict__ outp,
                                              float* __restrict__ pex,
                                              float* __restrict__ rws) {
    __shared__ char sXt[2][32 * 256];    // fp8 tile image (xb8 pre-swizzled), 8 KB each
    __shared__ short sK[2][64 * 36];     // kernel tile [q][t] bf16, stride 36 (conflict-free writes)
    __shared__ float sRow[64];

    const int tid = threadIdx.x;
    const int w = tid >> 6, lane = tid & 63;
    const int col = lane & 15, quad = lane >> 4;
    const int cx = col & 7;

    int b, th, qt;
    if (TSPLIT == 4) {
        b  = (blockIdx.x >> 1) & 3;
        th = (blockIdx.x & 1) | (((blockIdx.x >> 3) & 1) << 1);
        qt = blockIdx.x >> 4;
    } else if (TSPLIT == 2) {
        b  = (blockIdx.x & 7) >> 1;
        th = blockIdx.x & 1;
        qt = blockIdx.x >> 3;
    } else {
        b = blockIdx.x & 3;
        th = 0;
        qt = blockIdx.x >> 2;
    }
    const int q0 = qt * 64;
    const int t_base = th * (S / TSPLIT);
    const int NT = (S / TSPLIT) / 32;

    float temp = fmaxf(__expf(logt[0]), 1e-5f);
    float t2 = temp * temp;

    const unsigned char* xtb = xb8 + (size_t)b * S * D;
    const short* vtb = vt + (size_t)b * D * S;
    const float* sqb = sq + b * S;

    // gram A-frags (fp8): q-row q0 + w*16 + col, 8 bytes per k-step (swizzle-aware)
    long xq[8];
    {
        const unsigned char* xrow = xtb + (size_t)(q0 + w * 16 + col) * D;
        #pragma unroll
        for (int ks = 0; ks < 8; ks++)
            xq[ks] = *(const long*)(xrow + (((ks * 2 + (quad >> 1)) ^ cx) << 4) + (quad & 1) * 8);
    }
    float sqq[4];
    #pragma unroll
    for (int rr = 0; rr < 4; rr++)
        sqq[rr] = sqb[q0 + w * 16 + quad * 4 + rr];

    f32x4 acc[4][4];
    #pragma unroll
    for (int mi = 0; mi < 4; mi++)
        #pragma unroll
        for (int ni = 0; ni < 4; ni++)
            acc[mi][ni] = (f32x4){0.f, 0.f, 0.f, 0.f};
    float rs[4] = {0.f, 0.f, 0.f, 0.f};

    // prologue: async-stage tile 0 (8 KB: 2 chunks/thread)
    {
        const char* g = (const char*)(xtb + (size_t)t_base * D);
        #pragma unroll
        for (int p = 0; p < 2; p++) {
            int c = p * 256 + tid;
            g2lds16(g + c * 16, &sXt[0][c * 16]);
        }
    }

    for (int i = 0; i < NT; i++) {
        const int t0 = t_base + i * 32;
        const int cur = i & 1;
        __syncthreads();   // staging(i) landed + sK[(i-1)&1] written; PV_{i-2} reads done

        if (i + 1 < NT) {   // async-stage tile i+1
            const char* g = (const char*)(xtb + (size_t)(t0 + 32) * D);
            #pragma unroll
            for (int p = 0; p < 2; p++) {
                int c = p * 256 + tid;
                g2lds16(g + c * 16, &sXt[cur ^ 1][c * 16]);
            }
        }

        // Vt for PV_{i-1} (issue early, consume at end)
        bf16x8 vb[4];
        if (i > 0) {
            const int tp = t0 - 32;
            #pragma unroll
            for (int ni = 0; ni < 4; ni++)
                vb[ni] = *(const bf16x8*)(vtb + (size_t)(w * 64 + ni * 16 + col) * S + tp + quad * 8);
        }
        float sqt0 = sqb[t0 + col], sqt1 = sqb[t0 + 16 + col];

        // ---- gram (fp8): P[16 q][32 t] ----
        f32x4 p2v[2];
        p2v[0] = (f32x4){0.f, 0.f, 0.f, 0.f};
        p2v[1] = (f32x4){0.f, 0.f, 0.f, 0.f};
        #pragma unroll
        for (int ks = 0; ks < 8; ks++) {
            int co = (((ks * 2 + (quad >> 1)) ^ cx) << 4) + (quad & 1) * 8;
            long b0 = *(const long*)(&sXt[cur][col * 256 + co]);
            long b1 = *(const long*)(&sXt[cur][(col + 16) * 256 + co]);
            p2v[0] = MFMA8(xq[ks], b0, p2v[0]);
            p2v[1] = MFMA8(xq[ks], b1, p2v[1]);
        }

        // ---- Cauchy transform + rowsum + sK[cur] write ----
        #pragma unroll
        for (int t_ = 0; t_ < 2; t_++) {
            float sqt = t_ ? sqt1 : sqt0;
            int tg = t0 + t_ * 16 + col;
            #pragma unroll
            for (int rr = 0; rr < 4; rr++) {
                float d2 = fmaxf(sqq[rr] + sqt - 2.f * p2v[t_][rr], 0.f);
                float kv = t2 * __builtin_amdgcn_rcpf(t2 + d2);
                if (q0 + w * 16 + quad * 4 + rr == tg) kv = 1.f;   // exact diagonal
                rs[rr] += kv;
                sK[cur][(w * 16 + quad * 4 + rr) * 36 + t_ * 16 + col] = f2bf(kv);
            }
        }

        // ---- PV_{i-1} (bf16): acc[64 q][64 d-strip] += K_{i-1} @ V^T ----
        if (i > 0) {
            #pragma unroll
            for (int mi = 0; mi < 4; mi++) {
                bf16x8 af = *(const bf16x8*)(&sK[cur ^ 1][(mi * 16 + col) * 36 + quad * 8]);
                #pragma unroll
                for (int ni = 0; ni < 4; ni++)
                    acc[mi][ni] = MFMA(af, vb[ni], acc[mi][ni]);
            }
        }
    }

    // ---- epilogue: final PV ----
    __syncthreads();
    {
        const int tp = t_base + (NT - 1) * 32;
        const int cur = (NT - 1) & 1;
        bf16x8 vb[4];
        #pragma unroll
        for (int ni = 0; ni < 4; ni++)
            vb[ni] = *(const bf16x8*)(vtb + (size_t)(w * 64 + ni * 16 + col) * S + tp + quad * 8);
        #pragma unroll
        for (int mi = 0; mi < 4; mi++) {
            bf16x8 af = *(const bf16x8*)(&sK[cur][(mi * 16 + col) * 36 + quad * 8]);
            #pragma unroll
            for (int ni = 0; ni < 4; ni++)
                acc[mi][ni] = MFMA(af, vb[ni], acc[mi][ni]);
        }
    }

    // rowsum: reduce over 16 t-cols in wave; unique writer per q-row
    #pragma unroll
    for (int rr = 0; rr < 4; rr++) {
        float v = rs[rr];
        v += __shfl_xor(v, 1, 64);
        v += __shfl_xor(v, 2, 64);
        v += __shfl_xor(v, 4, 64);
        v += __shfl_xor(v, 8, 64);
        if (col == 0) sRow[w * 16 + quad * 4 + rr] = v;
    }
    __syncthreads();

    if (TSPLIT == 1) {
        float* ob = outp + (size_t)(b * S + q0) * D;
        #pragma unroll
        for (int mi = 0; mi < 4; mi++)
            #pragma unroll
            for (int rr = 0; rr < 4; rr++) {
                float rinv = __builtin_amdgcn_rcpf(fmaxf(sRow[mi * 16 + quad * 4 + rr], 1e-8f));
                #pragma unroll
                for (int ni = 0; ni < 4; ni++)
                    ob[(size_t)(mi * 16 + quad * 4 + rr) * D + w * 64 + ni * 16 + col] =
                        acc[mi][ni][rr] * rinv;
            }
    } else {
        if (tid < 64) rws[(size_t)th * NB * S + b * S + q0 + tid] = sRow[tid];
        float* ob = (th == 0 ? outp : pex + (size_t)(th - 1) * NB * S * D) + (size_t)(b * S + q0) * D;
        #pragma unroll
        for (int mi = 0; mi < 4; mi++)
            #pragma unroll
            for (int rr = 0; rr < 4; rr++)
                #pragma unroll
                for (int ni = 0; ni < 4; ni++)
                    ob[(size_t)(mi * 16 + quad * 4 + rr) * D + w * 64 + ni * 16 + col] =
                        acc[mi][ni][rr];
    }
}

// ---------------- combine: out = sum(partials) / max(sum(rowsums), eps) ----------------
template <int TSPLIT>
__global__ __launch_bounds__(256) void k_combine(float* __restrict__ outp,
                                                 const float* __restrict__ pex,
                                                 const float* __restrict__ rws) {
    int i4 = blockIdx.x * 256 + threadIdx.x;
    int gs = i4 >> 6;   // D/4 = 64 float4 per row
    float sum = rws[gs];
    #pragma unroll
    for (int p = 1; p < TSPLIT; p++) sum += rws[(size_t)p * NB * S + gs];
    float rinv = __builtin_amdgcn_rcpf(fmaxf(sum, 1e-8f));
    float4 o = ((const float4*)outp)[i4];
    #pragma unroll
    for (int p = 1; p < TSPLIT; p++) {
        float4 e = ((const float4*)(pex + (size_t)(p - 1) * NB * S * D))[i4];
        o.x += e.x; o.y += e.y; o.z += e.z; o.w += e.w;
    }
    o.x *= rinv; o.y *= rinv; o.z *= rinv; o.w *= rinv;
    ((float4*)outp)[i4] = o;
}

extern "C" void kernel_launch(void* const* d_in, const int* in_sizes, int n_in,
                              void* d_out, int out_size, void* d_ws, size_t ws_size,
                              hipStream_t stream) {
    const float* x    = (const float*)d_in[0];
    const float* Wv   = (const float*)d_in[1];
    const float* bv   = (const float*)d_in[2];
    const float* logt = (const float*)d_in[3];
    float* out = (float*)d_out;

    char* ws = (char*)d_ws;
    unsigned char* xb8 = (unsigned char*)ws;          // fp8 x (swizzled) [B][S][D]  4 MB
    short* vt  = (short*)(ws + 4194304);              // bf16 V^T [B][D][S]          8 MB
    float* sq  = (float*)(ws + 12582912);             // ||x||^2  [B][S]             64 KB
    float* rws = (float*)(ws + 12648448);             // rowsums  [T][B][S]          256 KB
    const size_t pex_off = 12910592u;
    const size_t P = (size_t)NB * S * D * 4u;         // 16.78 MB per partial

    k_vprojx<<<NB * (S / 64), 512, 0, stream>>>(x, Wv, bv, xb8, sq, vt);

    const size_t need4 = pex_off + 3u * P;
    const size_t need2 = pex_off + 1u * P;
    if (ws_size >= need4) {
        float* pex = (float*)(ws + pex_off);
        k_attn<4><<<NB * (S / 64) * 4, 256, 0, stream>>>(xb8, vt, sq, logt, out, pex, rws);
        k_combine<4><<<(NB * S * D / 4) / 256, 256, 0, stream>>>(out, pex, rws);
    } else if (ws_size >= need2) {
        float* pex = (float*)(ws + pex_off);
        k_attn<2><<<NB * (S / 64) * 2, 256, 0, stream>>>(xb8, vt, sq, logt, out, pex, rws);
        k_combine<2><<<(NB * S * D / 4) / 256, 256, 0, stream>>>(out, pex, rws);
    } else {
        k_attn<1><<<NB * (S / 64), 256, 0, stream>>>(xb8, vt, sq, logt, out, nullptr, nullptr);
    }
}